// Round 1
// baseline (1620.067 us; speedup 1.0000x reference)
//
#include <hip/hip_runtime.h>
#include <hip/hip_bf16.h>
#include <cstdint>
#include <cstddef>

// Problem constants (from reference)
#define NBAGS  16
#define NNODES 5000
#define NEDGES 160000
#define DIN    128
#define DENC   256   // == D_GNN
#define DFC    128
#define NCLS   2

// ---------------------------------------------------------------------------
// GEMM: C[rows x 256] = act( A1[rows x K]@W1[K x 256] (+ A2[rows x K]@W2) + bias )
// Row-major everywhere. BM=BN=128, BK=16, 256 threads, 8x8 micro (split 2x 4-wide).
// ---------------------------------------------------------------------------
template<bool DUAL, bool RELU>
__global__ __launch_bounds__(256)
void gemm_kernel(const float* __restrict__ A1, const float* __restrict__ W1,
                 const float* __restrict__ A2, const float* __restrict__ W2,
                 const float* __restrict__ bias, float* __restrict__ C,
                 int rows, int K)
{
    __shared__ __align__(16) float As[16][132];  // [k][m], padded stride
    __shared__ __align__(16) float Bs[16][132];  // [k][n], padded stride

    const int tid = threadIdx.x;
    const int tx = tid & 15;        // col group 0..15
    const int ty = tid >> 4;        // row group 0..15
    const int row0 = blockIdx.x * 128;
    const int n0 = blockIdx.y * 128;

    float acc[2][2][4][4];
#pragma unroll
    for (int a = 0; a < 2; ++a)
#pragma unroll
        for (int b = 0; b < 2; ++b)
#pragma unroll
            for (int i = 0; i < 4; ++i)
#pragma unroll
                for (int j = 0; j < 4; ++j) acc[a][b][i][j] = 0.f;

    const int npass = DUAL ? 2 : 1;
    for (int pass = 0; pass < npass; ++pass) {
        const float* __restrict__ A = (DUAL && pass) ? A2 : A1;
        const float* __restrict__ W = (DUAL && pass) ? W2 : W1;

        for (int k0 = 0; k0 < K; k0 += 16) {
            // ---- load A tile (128 rows x 16 k), store transposed As[k][m]
            {
                const int m  = tid >> 2;          // 0..63
                const int kk = (tid & 3) * 4;     // 0,4,8,12
#pragma unroll
                for (int h = 0; h < 2; ++h) {
                    const int r = row0 + m + h * 64;
                    float4 v = make_float4(0.f, 0.f, 0.f, 0.f);
                    if (r < rows) v = *(const float4*)(A + (size_t)r * K + k0 + kk);
                    As[kk + 0][m + h * 64] = v.x;
                    As[kk + 1][m + h * 64] = v.y;
                    As[kk + 2][m + h * 64] = v.z;
                    As[kk + 3][m + h * 64] = v.w;
                }
            }
            // ---- load B tile (16 k x 128 n)
            {
                const int kk = tid >> 4;           // 0..15
                const int n  = (tid & 15) * 8;     // 0..120
                const float* Wp = W + (size_t)(k0 + kk) * 256 + n0 + n;
                float4 v0 = *(const float4*)(Wp);
                float4 v1 = *(const float4*)(Wp + 4);
                *(float4*)&Bs[kk][n]     = v0;
                *(float4*)&Bs[kk][n + 4] = v1;
            }
            __syncthreads();
#pragma unroll
            for (int k = 0; k < 16; ++k) {
                float4 a0 = *(const float4*)&As[k][4 * ty];
                float4 a1 = *(const float4*)&As[k][64 + 4 * ty];
                float4 b0 = *(const float4*)&Bs[k][4 * tx];
                float4 b1 = *(const float4*)&Bs[k][64 + 4 * tx];
                const float ar[2][4] = {{a0.x, a0.y, a0.z, a0.w}, {a1.x, a1.y, a1.z, a1.w}};
                const float br[2][4] = {{b0.x, b0.y, b0.z, b0.w}, {b1.x, b1.y, b1.z, b1.w}};
#pragma unroll
                for (int ri = 0; ri < 2; ++ri)
#pragma unroll
                    for (int ci = 0; ci < 2; ++ci)
#pragma unroll
                        for (int i = 0; i < 4; ++i)
#pragma unroll
                            for (int j = 0; j < 4; ++j)
                                acc[ri][ci][i][j] = fmaf(ar[ri][i], br[ci][j], acc[ri][ci][i][j]);
            }
            __syncthreads();
        }
    }

    // ---- epilogue: bias + optional relu, float4 stores
#pragma unroll
    for (int ri = 0; ri < 2; ++ri) {
#pragma unroll
        for (int i = 0; i < 4; ++i) {
            const int r = row0 + ri * 64 + 4 * ty + i;
            if (r < rows) {
#pragma unroll
                for (int ci = 0; ci < 2; ++ci) {
                    const int cb = n0 + ci * 64 + 4 * tx;
                    float4 bv = *(const float4*)(bias + cb);
                    float4 o;
                    o.x = acc[ri][ci][i][0] + bv.x;
                    o.y = acc[ri][ci][i][1] + bv.y;
                    o.z = acc[ri][ci][i][2] + bv.z;
                    o.w = acc[ri][ci][i][3] + bv.w;
                    if (RELU) {
                        o.x = fmaxf(o.x, 0.f); o.y = fmaxf(o.y, 0.f);
                        o.z = fmaxf(o.z, 0.f); o.w = fmaxf(o.w, 0.f);
                    }
                    *(float4*)(C + (size_t)r * 256 + cb) = o;
                }
            }
        }
    }
}

// ---------------------------------------------------------------------------
// CSR build: count -> scan -> fill. edges laid out [bag][2][E], int32.
// ---------------------------------------------------------------------------
__global__ __launch_bounds__(256)
void count_kernel(const int* __restrict__ edges, int* __restrict__ cnt)
{
    const int e = blockIdx.x * 256 + threadIdx.x;
    const int b = blockIdx.y;
    if (e < NEDGES) {
        const int dst = edges[(size_t)b * 2 * NEDGES + NEDGES + e];
        atomicAdd(&cnt[b * NNODES + dst], 1);
    }
}

__global__ __launch_bounds__(1024)
void scan_kernel(const int* __restrict__ cnt, int* __restrict__ rowptr)
{
    const int b = blockIdx.x;
    const int t = threadIdx.x;
    __shared__ int sh[1024];
    const int CH = 5;                     // 1024*5 >= 5000
    const int base = t * CH;
    int local[CH];
    int sum = 0;
#pragma unroll
    for (int i = 0; i < CH; ++i) {
        const int g = base + i;
        const int v = (g < NNODES) ? cnt[b * NNODES + g] : 0;
        local[i] = v; sum += v;
    }
    sh[t] = sum;
    __syncthreads();
    for (int off = 1; off < 1024; off <<= 1) {
        const int add = (t >= off) ? sh[t - off] : 0;
        __syncthreads();
        sh[t] += add;
        __syncthreads();
    }
    int run = sh[t] - sum;                // exclusive prefix
#pragma unroll
    for (int i = 0; i < CH; ++i) {
        const int g = base + i;
        if (g < NNODES) rowptr[b * (NNODES + 1) + g] = run;
        run += local[i];
    }
    if (t == 1023) rowptr[b * (NNODES + 1) + NNODES] = run;  // == NEDGES
}

__global__ __launch_bounds__(256)
void fill_kernel(const int* __restrict__ edges, const int* __restrict__ rowptr,
                 int* __restrict__ fillc, int* __restrict__ colidx)
{
    const int e = blockIdx.x * 256 + threadIdx.x;
    const int b = blockIdx.y;
    if (e < NEDGES) {
        const int* eb = edges + (size_t)b * 2 * NEDGES;
        const int src = eb[e];
        const int dst = eb[NEDGES + e];
        const int pos = rowptr[b * (NNODES + 1) + dst] + atomicAdd(&fillc[b * NNODES + dst], 1);
        colidx[(size_t)b * NEDGES + pos] = src;
    }
}

// ---------------------------------------------------------------------------
// Mean aggregation (pull): M[b,i,:] = (1/max(deg,1)) * sum_{s in N(i)} X[b,s,:]
// One block per (node, bag); thread d owns feature d.
// ---------------------------------------------------------------------------
__global__ __launch_bounds__(256)
void agg_mean_kernel(const float* __restrict__ X, const int* __restrict__ rowptr,
                     const int* __restrict__ colidx, float* __restrict__ M)
{
    const int node = blockIdx.x;
    const int b = blockIdx.y;
    const int d = threadIdx.x;
    const int* rp = rowptr + b * (NNODES + 1);
    int s = rp[node];
    const int e = rp[node + 1];
    const float inv = 1.0f / fmaxf((float)(e - s), 1.0f);
    const float* Xb = X + (size_t)b * NNODES * DENC;
    const int* ci = colidx + (size_t)b * NEDGES;
    __shared__ int idx[256];
    float a0 = 0.f, a1 = 0.f, a2 = 0.f, a3 = 0.f;
    while (s < e) {
        const int c = min(e - s, 256);
        __syncthreads();
        if (d < c) idx[d] = ci[s + d];
        __syncthreads();
        int j = 0;
        for (; j + 4 <= c; j += 4) {
            const int i0 = idx[j], i1 = idx[j + 1], i2 = idx[j + 2], i3 = idx[j + 3];
            a0 += Xb[(size_t)i0 * DENC + d];
            a1 += Xb[(size_t)i1 * DENC + d];
            a2 += Xb[(size_t)i2 * DENC + d];
            a3 += Xb[(size_t)i3 * DENC + d];
        }
        for (; j < c; ++j) a0 += Xb[(size_t)idx[j] * DENC + d];
        s += c;
    }
    M[((size_t)b * NNODES + node) * DENC + d] = (a0 + a1 + a2 + a3) * inv;
}

// ---------------------------------------------------------------------------
// emb[bag] = sum over nodes of G2 rows
// ---------------------------------------------------------------------------
__global__ __launch_bounds__(1024)
void reduce_emb_kernel(const float* __restrict__ G2, float* __restrict__ emb, int bagBase)
{
    const int b = blockIdx.x;
    const int t = threadIdx.x;
    const int d = t & 255;
    const int r = t >> 8;
    const float* P = G2 + (size_t)b * NNODES * DENC;
    float acc = 0.f;
    for (int n = r; n < NNODES; n += 4) acc += P[(size_t)n * DENC + d];
    __shared__ float sh[1024];
    sh[t] = acc;
    __syncthreads();
    if (r == 0) emb[(bagBase + b) * DENC + d] = sh[d] + sh[256 + d] + sh[512 + d] + sh[768 + d];
}

// ---------------------------------------------------------------------------
// classifier: out[b] = relu(emb[b]@Wc1 + bc1) @ Wc2 + bc2
// ---------------------------------------------------------------------------
__global__ __launch_bounds__(128)
void classifier_kernel(const float* __restrict__ emb, const float* __restrict__ Wc1,
                       const float* __restrict__ bc1, const float* __restrict__ Wc2,
                       const float* __restrict__ bc2, float* __restrict__ out)
{
    const int b = blockIdx.x;
    const int t = threadIdx.x;  // 128
    __shared__ float se[DENC];
    se[t] = emb[b * DENC + t];
    se[128 + t] = emb[b * DENC + 128 + t];
    __syncthreads();
    float h = bc1[t];
    for (int k = 0; k < DENC; ++k) h = fmaf(se[k], Wc1[k * DFC + t], h);
    h = fmaxf(h, 0.f);
    __shared__ float s0[128], s1[128];
    s0[t] = h * Wc2[t * NCLS + 0];
    s1[t] = h * Wc2[t * NCLS + 1];
    __syncthreads();
    for (int off = 64; off > 0; off >>= 1) {
        if (t < off) { s0[t] += s0[t + off]; s1[t] += s1[t + off]; }
        __syncthreads();
    }
    if (t == 0) {
        out[b * NCLS + 0] = s0[0] + bc2[0];
        out[b * NCLS + 1] = s1[0] + bc2[1];
    }
}

// ---------------------------------------------------------------------------
extern "C" void kernel_launch(void* const* d_in, const int* in_sizes, int n_in,
                              void* d_out, int out_size, void* d_ws, size_t ws_size,
                              hipStream_t stream)
{
    const float* x    = (const float*)d_in[0];
    const int*   edges= (const int*)d_in[1];   // int32 (JAX x64 disabled)
    const float* We   = (const float*)d_in[2];
    const float* be   = (const float*)d_in[3];
    const float* Wl1  = (const float*)d_in[4];
    const float* bl1  = (const float*)d_in[5];
    const float* Wr1  = (const float*)d_in[6];
    const float* Wl2  = (const float*)d_in[7];
    const float* bl2  = (const float*)d_in[8];
    const float* Wr2  = (const float*)d_in[9];
    // d_in[10..12] = Wlp, blp, Wrp: dead code (softmax over 1 cluster == 1)
    const float* Wc1  = (const float*)d_in[13];
    const float* bc1  = (const float*)d_in[14];
    const float* Wc2  = (const float*)d_in[15];
    const float* bc2  = (const float*)d_in[16];
    float* out = (float*)d_out;

    // choose bag-group size G based on workspace
    auto bytesFor = [](int G) -> size_t {
        size_t big = (size_t)G * NNODES * DENC * 4;   // one feature buffer
        size_t tot = 3 * ((big + 255) & ~(size_t)255);
        tot += ((size_t)G * (NNODES + 1) * 4 + 255) & ~(size_t)255;  // rowptr
        tot += 2 * (((size_t)G * NNODES * 4 + 255) & ~(size_t)255);  // cnt, fill
        tot += ((size_t)G * NEDGES * 4 + 255) & ~(size_t)255;        // colidx
        tot += ((size_t)NBAGS * DENC * 4 + 255) & ~(size_t)255;      // emb
        return tot + 1024;
    };
    int G = NBAGS;
    while (G > 1 && bytesFor(G) > ws_size) G >>= 1;

    char* p = (char*)d_ws;
    auto alloc = [&](size_t bytes) -> char* {
        char* r = p;
        p += (bytes + 255) & ~(size_t)255;
        return r;
    };
    float* H      = (float*)alloc((size_t)G * NNODES * DENC * 4);  // h, then mean2
    float* Mb     = (float*)alloc((size_t)G * NNODES * DENC * 4);  // mean1, then g2
    float* Gb     = (float*)alloc((size_t)G * NNODES * DENC * 4);  // g1
    int*   rowptr = (int*)  alloc((size_t)G * (NNODES + 1) * 4);
    int*   cnt    = (int*)  alloc((size_t)G * NNODES * 4);
    int*   fillc  = (int*)  alloc((size_t)G * NNODES * 4);
    int*   colidx = (int*)  alloc((size_t)G * NEDGES * 4);
    float* emb    = (float*)alloc((size_t)NBAGS * DENC * 4);

    for (int bagBase = 0; bagBase < NBAGS; bagBase += G) {
        const int g = (bagBase + G <= NBAGS) ? G : (NBAGS - bagBase);
        const int rows = g * NNODES;
        const float* xg = x + (size_t)bagBase * NNODES * DIN;
        const int*   eg = edges + (size_t)bagBase * 2 * NEDGES;

        hipMemsetAsync(cnt,   0, (size_t)g * NNODES * 4, stream);
        hipMemsetAsync(fillc, 0, (size_t)g * NNODES * 4, stream);

        dim3 gemm_grid((rows + 127) / 128, 2);

        // encoder: H = relu(x @ We + be)
        gemm_kernel<false, true><<<gemm_grid, 256, 0, stream>>>(
            xg, We, nullptr, nullptr, be, H, rows, DIN);

        // CSR build (shared by both SAGE layers)
        count_kernel<<<dim3(NEDGES / 256, g), 256, 0, stream>>>(eg, cnt);
        scan_kernel<<<g, 1024, 0, stream>>>(cnt, rowptr);
        fill_kernel<<<dim3(NEDGES / 256, g), 256, 0, stream>>>(eg, rowptr, fillc, colidx);

        // layer 1
        agg_mean_kernel<<<dim3(NNODES, g), 256, 0, stream>>>(H, rowptr, colidx, Mb);
        gemm_kernel<true, true><<<gemm_grid, 256, 0, stream>>>(
            Mb, Wl1, H, Wr1, bl1, Gb, rows, DENC);

        // layer 2 (mean2 -> H, g2 -> Mb)
        agg_mean_kernel<<<dim3(NNODES, g), 256, 0, stream>>>(Gb, rowptr, colidx, H);
        gemm_kernel<true, true><<<gemm_grid, 256, 0, stream>>>(
            H, Wl2, Gb, Wr2, bl2, Mb, rows, DENC);

        // emb[bag] = sum over nodes of g2
        reduce_emb_kernel<<<g, 1024, 0, stream>>>(Mb, emb, bagBase);
    }

    classifier_kernel<<<NBAGS, 128, 0, stream>>>(emb, Wc1, bc1, Wc2, bc2, out);
}

// Round 2
// 1285.291 us; speedup vs baseline: 1.2605x; 1.2605x over previous
//
#include <hip/hip_runtime.h>
#include <hip/hip_bf16.h>
#include <cstdint>
#include <cstddef>

// Problem constants (from reference)
#define NBAGS  16
#define NNODES 5000
#define NEDGES 160000
#define DIN    128
#define DENC   256   // == D_GNN
#define DFC    128
#define NCLS   2

// ---------------------------------------------------------------------------
// GEMM: C[rows x 256] = act( A1[rows x K]@W1[K x 256] (+ A2[rows x K]@W2) + bias )
// Row-major everywhere. BM=BN=128, BK=16, 256 threads, 8x8 micro (split 2x 4-wide).
// ---------------------------------------------------------------------------
template<bool DUAL, bool RELU>
__global__ __launch_bounds__(256)
void gemm_kernel(const float* __restrict__ A1, const float* __restrict__ W1,
                 const float* __restrict__ A2, const float* __restrict__ W2,
                 const float* __restrict__ bias, float* __restrict__ C,
                 int rows, int K)
{
    __shared__ __align__(16) float As[16][132];  // [k][m], padded stride
    __shared__ __align__(16) float Bs[16][132];  // [k][n], padded stride

    const int tid = threadIdx.x;
    const int tx = tid & 15;        // col group 0..15
    const int ty = tid >> 4;        // row group 0..15
    const int row0 = blockIdx.x * 128;
    const int n0 = blockIdx.y * 128;

    float acc[2][2][4][4];
#pragma unroll
    for (int a = 0; a < 2; ++a)
#pragma unroll
        for (int b = 0; b < 2; ++b)
#pragma unroll
            for (int i = 0; i < 4; ++i)
#pragma unroll
                for (int j = 0; j < 4; ++j) acc[a][b][i][j] = 0.f;

    const int npass = DUAL ? 2 : 1;
    for (int pass = 0; pass < npass; ++pass) {
        const float* __restrict__ A = (DUAL && pass) ? A2 : A1;
        const float* __restrict__ W = (DUAL && pass) ? W2 : W1;

        for (int k0 = 0; k0 < K; k0 += 16) {
            // ---- load A tile (128 rows x 16 k), store transposed As[k][m]
            {
                const int m  = tid >> 2;          // 0..63
                const int kk = (tid & 3) * 4;     // 0,4,8,12
#pragma unroll
                for (int h = 0; h < 2; ++h) {
                    const int r = row0 + m + h * 64;
                    float4 v = make_float4(0.f, 0.f, 0.f, 0.f);
                    if (r < rows) v = *(const float4*)(A + (size_t)r * K + k0 + kk);
                    As[kk + 0][m + h * 64] = v.x;
                    As[kk + 1][m + h * 64] = v.y;
                    As[kk + 2][m + h * 64] = v.z;
                    As[kk + 3][m + h * 64] = v.w;
                }
            }
            // ---- load B tile (16 k x 128 n)
            {
                const int kk = tid >> 4;           // 0..15
                const int n  = (tid & 15) * 8;     // 0..120
                const float* Wp = W + (size_t)(k0 + kk) * 256 + n0 + n;
                float4 v0 = *(const float4*)(Wp);
                float4 v1 = *(const float4*)(Wp + 4);
                *(float4*)&Bs[kk][n]     = v0;
                *(float4*)&Bs[kk][n + 4] = v1;
            }
            __syncthreads();
#pragma unroll
            for (int k = 0; k < 16; ++k) {
                float4 a0 = *(const float4*)&As[k][4 * ty];
                float4 a1 = *(const float4*)&As[k][64 + 4 * ty];
                float4 b0 = *(const float4*)&Bs[k][4 * tx];
                float4 b1 = *(const float4*)&Bs[k][64 + 4 * tx];
                const float ar[2][4] = {{a0.x, a0.y, a0.z, a0.w}, {a1.x, a1.y, a1.z, a1.w}};
                const float br[2][4] = {{b0.x, b0.y, b0.z, b0.w}, {b1.x, b1.y, b1.z, b1.w}};
#pragma unroll
                for (int ri = 0; ri < 2; ++ri)
#pragma unroll
                    for (int ci = 0; ci < 2; ++ci)
#pragma unroll
                        for (int i = 0; i < 4; ++i)
#pragma unroll
                            for (int j = 0; j < 4; ++j)
                                acc[ri][ci][i][j] = fmaf(ar[ri][i], br[ci][j], acc[ri][ci][i][j]);
            }
            __syncthreads();
        }
    }

    // ---- epilogue: bias + optional relu, float4 stores
#pragma unroll
    for (int ri = 0; ri < 2; ++ri) {
#pragma unroll
        for (int i = 0; i < 4; ++i) {
            const int r = row0 + ri * 64 + 4 * ty + i;
            if (r < rows) {
#pragma unroll
                for (int ci = 0; ci < 2; ++ci) {
                    const int cb = n0 + ci * 64 + 4 * tx;
                    float4 bv = *(const float4*)(bias + cb);
                    float4 o;
                    o.x = acc[ri][ci][i][0] + bv.x;
                    o.y = acc[ri][ci][i][1] + bv.y;
                    o.z = acc[ri][ci][i][2] + bv.z;
                    o.w = acc[ri][ci][i][3] + bv.w;
                    if (RELU) {
                        o.x = fmaxf(o.x, 0.f); o.y = fmaxf(o.y, 0.f);
                        o.z = fmaxf(o.z, 0.f); o.w = fmaxf(o.w, 0.f);
                    }
                    *(float4*)(C + (size_t)r * 256 + cb) = o;
                }
            }
        }
    }
}

// ---------------------------------------------------------------------------
// CSR build: count -> scan -> fill. edges laid out [bag][2][E], int32.
// ---------------------------------------------------------------------------
__global__ __launch_bounds__(256)
void count_kernel(const int* __restrict__ edges, int* __restrict__ cnt)
{
    const int e = blockIdx.x * 256 + threadIdx.x;
    const int b = blockIdx.y;
    if (e < NEDGES) {
        const int dst = edges[(size_t)b * 2 * NEDGES + NEDGES + e];
        atomicAdd(&cnt[b * NNODES + dst], 1);
    }
}

__global__ __launch_bounds__(1024)
void scan_kernel(const int* __restrict__ cnt, int* __restrict__ rowptr)
{
    const int b = blockIdx.x;
    const int t = threadIdx.x;
    __shared__ int sh[1024];
    const int CH = 5;                     // 1024*5 >= 5000
    const int base = t * CH;
    int local[CH];
    int sum = 0;
#pragma unroll
    for (int i = 0; i < CH; ++i) {
        const int g = base + i;
        const int v = (g < NNODES) ? cnt[b * NNODES + g] : 0;
        local[i] = v; sum += v;
    }
    sh[t] = sum;
    __syncthreads();
    for (int off = 1; off < 1024; off <<= 1) {
        const int add = (t >= off) ? sh[t - off] : 0;
        __syncthreads();
        sh[t] += add;
        __syncthreads();
    }
    int run = sh[t] - sum;                // exclusive prefix
#pragma unroll
    for (int i = 0; i < CH; ++i) {
        const int g = base + i;
        if (g < NNODES) rowptr[b * (NNODES + 1) + g] = run;
        run += local[i];
    }
    if (t == 1023) rowptr[b * (NNODES + 1) + NNODES] = run;  // == NEDGES
}

__global__ __launch_bounds__(256)
void fill_kernel(const int* __restrict__ edges, const int* __restrict__ rowptr,
                 int* __restrict__ fillc, int* __restrict__ colidx)
{
    const int e = blockIdx.x * 256 + threadIdx.x;
    const int b = blockIdx.y;
    if (e < NEDGES) {
        const int* eb = edges + (size_t)b * 2 * NEDGES;
        const int src = eb[e];
        const int dst = eb[NEDGES + e];
        const int pos = rowptr[b * (NNODES + 1) + dst] + atomicAdd(&fillc[b * NNODES + dst], 1);
        colidx[(size_t)b * NEDGES + pos] = src;
    }
}

// ---------------------------------------------------------------------------
// Mean aggregation (pull): M[b,i,:] = (1/max(deg,1)) * sum_{s in N(i)} X[b,s,:]
// One block per (node, bag); thread d owns feature d.
// ---------------------------------------------------------------------------
__global__ __launch_bounds__(256)
void agg_mean_kernel(const float* __restrict__ X, const int* __restrict__ rowptr,
                     const int* __restrict__ colidx, float* __restrict__ M)
{
    const int node = blockIdx.x;
    const int b = blockIdx.y;
    const int d = threadIdx.x;
    const int* rp = rowptr + b * (NNODES + 1);
    int s = rp[node];
    const int e = rp[node + 1];
    const float inv = 1.0f / fmaxf((float)(e - s), 1.0f);
    const float* Xb = X + (size_t)b * NNODES * DENC;
    const int* ci = colidx + (size_t)b * NEDGES;
    __shared__ int idx[256];
    float a0 = 0.f, a1 = 0.f, a2 = 0.f, a3 = 0.f;
    while (s < e) {
        const int c = min(e - s, 256);
        __syncthreads();
        if (d < c) idx[d] = ci[s + d];
        __syncthreads();
        int j = 0;
        for (; j + 4 <= c; j += 4) {
            const int i0 = idx[j], i1 = idx[j + 1], i2 = idx[j + 2], i3 = idx[j + 3];
            a0 += Xb[(size_t)i0 * DENC + d];
            a1 += Xb[(size_t)i1 * DENC + d];
            a2 += Xb[(size_t)i2 * DENC + d];
            a3 += Xb[(size_t)i3 * DENC + d];
        }
        for (; j < c; ++j) a0 += Xb[(size_t)idx[j] * DENC + d];
        s += c;
    }
    M[((size_t)b * NNODES + node) * DENC + d] = (a0 + a1 + a2 + a3) * inv;
}

// ---------------------------------------------------------------------------
// emb[bag] += partial column-sum of G2 rows. Grid: (chunks, bags).
// emb must be zeroed before. 40 chunks x 125 nodes = 5000.
// ---------------------------------------------------------------------------
#define EMB_CHUNKS 40
__global__ __launch_bounds__(256)
void reduce_emb_kernel(const float* __restrict__ G2, float* __restrict__ emb, int bagBase)
{
    const int chunk = blockIdx.x;
    const int b = blockIdx.y;
    const int d = threadIdx.x;             // feature 0..255
    const int n0 = chunk * (NNODES / EMB_CHUNKS);
    const int n1 = n0 + (NNODES / EMB_CHUNKS);
    const float* P = G2 + ((size_t)b * NNODES + n0) * DENC + d;
    float acc = 0.f;
    for (int n = n0; n < n1; ++n) {
        acc += *P;
        P += DENC;
    }
    atomicAdd(&emb[(bagBase + b) * DENC + d], acc);
}

// ---------------------------------------------------------------------------
// classifier: out[b] = relu(emb[b]@Wc1 + bc1) @ Wc2 + bc2
// ---------------------------------------------------------------------------
__global__ __launch_bounds__(128)
void classifier_kernel(const float* __restrict__ emb, const float* __restrict__ Wc1,
                       const float* __restrict__ bc1, const float* __restrict__ Wc2,
                       const float* __restrict__ bc2, float* __restrict__ out)
{
    const int b = blockIdx.x;
    const int t = threadIdx.x;  // 128
    __shared__ float se[DENC];
    se[t] = emb[b * DENC + t];
    se[128 + t] = emb[b * DENC + 128 + t];
    __syncthreads();
    float h = bc1[t];
    for (int k = 0; k < DENC; ++k) h = fmaf(se[k], Wc1[k * DFC + t], h);
    h = fmaxf(h, 0.f);
    __shared__ float s0[128], s1[128];
    s0[t] = h * Wc2[t * NCLS + 0];
    s1[t] = h * Wc2[t * NCLS + 1];
    __syncthreads();
    for (int off = 64; off > 0; off >>= 1) {
        if (t < off) { s0[t] += s0[t + off]; s1[t] += s1[t + off]; }
        __syncthreads();
    }
    if (t == 0) {
        out[b * NCLS + 0] = s0[0] + bc2[0];
        out[b * NCLS + 1] = s1[0] + bc2[1];
    }
}

// ---------------------------------------------------------------------------
extern "C" void kernel_launch(void* const* d_in, const int* in_sizes, int n_in,
                              void* d_out, int out_size, void* d_ws, size_t ws_size,
                              hipStream_t stream)
{
    const float* x    = (const float*)d_in[0];
    const int*   edges= (const int*)d_in[1];   // int32 (JAX x64 disabled)
    const float* We   = (const float*)d_in[2];
    const float* be   = (const float*)d_in[3];
    const float* Wl1  = (const float*)d_in[4];
    const float* bl1  = (const float*)d_in[5];
    const float* Wr1  = (const float*)d_in[6];
    const float* Wl2  = (const float*)d_in[7];
    const float* bl2  = (const float*)d_in[8];
    const float* Wr2  = (const float*)d_in[9];
    // d_in[10..12] = Wlp, blp, Wrp: dead code (softmax over 1 cluster == 1)
    const float* Wc1  = (const float*)d_in[13];
    const float* bc1  = (const float*)d_in[14];
    const float* Wc2  = (const float*)d_in[15];
    const float* bc2  = (const float*)d_in[16];
    float* out = (float*)d_out;

    // choose bag-group size G based on workspace
    auto bytesFor = [](int G) -> size_t {
        size_t big = (size_t)G * NNODES * DENC * 4;   // one feature buffer
        size_t tot = 3 * ((big + 255) & ~(size_t)255);
        tot += ((size_t)G * (NNODES + 1) * 4 + 255) & ~(size_t)255;  // rowptr
        tot += 2 * (((size_t)G * NNODES * 4 + 255) & ~(size_t)255);  // cnt, fill
        tot += ((size_t)G * NEDGES * 4 + 255) & ~(size_t)255;        // colidx
        tot += ((size_t)NBAGS * DENC * 4 + 255) & ~(size_t)255;      // emb
        return tot + 1024;
    };
    int G = NBAGS;
    while (G > 1 && bytesFor(G) > ws_size) G >>= 1;

    char* p = (char*)d_ws;
    auto alloc = [&](size_t bytes) -> char* {
        char* r = p;
        p += (bytes + 255) & ~(size_t)255;
        return r;
    };
    float* H      = (float*)alloc((size_t)G * NNODES * DENC * 4);  // h, then mean2
    float* Mb     = (float*)alloc((size_t)G * NNODES * DENC * 4);  // mean1, then g2
    float* Gb     = (float*)alloc((size_t)G * NNODES * DENC * 4);  // g1
    int*   rowptr = (int*)  alloc((size_t)G * (NNODES + 1) * 4);
    int*   cnt    = (int*)  alloc((size_t)G * NNODES * 4);
    int*   fillc  = (int*)  alloc((size_t)G * NNODES * 4);
    int*   colidx = (int*)  alloc((size_t)G * NEDGES * 4);
    float* emb    = (float*)alloc((size_t)NBAGS * DENC * 4);

    // emb accumulated via atomics -> zero it (ws is re-poisoned every launch)
    hipMemsetAsync(emb, 0, (size_t)NBAGS * DENC * 4, stream);

    for (int bagBase = 0; bagBase < NBAGS; bagBase += G) {
        const int g = (bagBase + G <= NBAGS) ? G : (NBAGS - bagBase);
        const int rows = g * NNODES;
        const float* xg = x + (size_t)bagBase * NNODES * DIN;
        const int*   eg = edges + (size_t)bagBase * 2 * NEDGES;

        hipMemsetAsync(cnt,   0, (size_t)g * NNODES * 4, stream);
        hipMemsetAsync(fillc, 0, (size_t)g * NNODES * 4, stream);

        dim3 gemm_grid((rows + 127) / 128, 2);

        // encoder: H = relu(x @ We + be)
        gemm_kernel<false, true><<<gemm_grid, 256, 0, stream>>>(
            xg, We, nullptr, nullptr, be, H, rows, DIN);

        // CSR build (shared by both SAGE layers)
        count_kernel<<<dim3(NEDGES / 256, g), 256, 0, stream>>>(eg, cnt);
        scan_kernel<<<g, 1024, 0, stream>>>(cnt, rowptr);
        fill_kernel<<<dim3(NEDGES / 256, g), 256, 0, stream>>>(eg, rowptr, fillc, colidx);

        // layer 1
        agg_mean_kernel<<<dim3(NNODES, g), 256, 0, stream>>>(H, rowptr, colidx, Mb);
        gemm_kernel<true, true><<<gemm_grid, 256, 0, stream>>>(
            Mb, Wl1, H, Wr1, bl1, Gb, rows, DENC);

        // layer 2 (mean2 -> H, g2 -> Mb)
        agg_mean_kernel<<<dim3(NNODES, g), 256, 0, stream>>>(Gb, rowptr, colidx, H);
        gemm_kernel<true, true><<<gemm_grid, 256, 0, stream>>>(
            H, Wl2, Gb, Wr2, bl2, Mb, rows, DENC);

        // emb[bag] += column-sums of g2 (parallel, atomic)
        reduce_emb_kernel<<<dim3(EMB_CHUNKS, g), 256, 0, stream>>>(Mb, emb, bagBase);
    }

    classifier_kernel<<<NBAGS, 128, 0, stream>>>(emb, Wc1, bc1, Wc2, bc2, out);
}

// Round 3
// 780.278 us; speedup vs baseline: 2.0763x; 1.6472x over previous
//
#include <hip/hip_runtime.h>
#include <hip/hip_bf16.h>
#include <cstdint>
#include <cstddef>

// Problem constants (from reference)
#define NBAGS  16
#define NNODES 5000
#define NEDGES 160000
#define DIN    128
#define DENC   256   // == D_GNN
#define DFC    128
#define NCLS   2

typedef __attribute__((ext_vector_type(8))) short short8;
typedef __attribute__((ext_vector_type(4))) float f32x4;

static __device__ __forceinline__ ushort f2b(float v) {
    __hip_bfloat16 b = __float2bfloat16(v);   // RNE
    return *reinterpret_cast<ushort*>(&b);
}
static __device__ __forceinline__ float b2f(ushort u) {
    return __uint_as_float((uint32_t)u << 16);
}

// ---------------------------------------------------------------------------
// bf16 MFMA GEMM: C[rows x 256] = act( A1@W1t^T (+ A2@W2t^T) + bias ), bf16 out
// A: row-major [rows x K] bf16. Wt: [256 x K] bf16 (pre-transposed weight).
// BM=BN=128, BK=32, 256 threads = 4 waves (2x2), wave tile 64x64 via 4x4
// mfma_f32_16x16x32_bf16 fragments. LDS rows padded to 40 elems (80 B) so
// fragment b128 reads are <=2-way bank aliased (free).
// ---------------------------------------------------------------------------
template<bool DUAL, bool RELU>
__global__ __launch_bounds__(256)
void gemm_bf16_kernel(const ushort* __restrict__ A1, const ushort* __restrict__ Wt1,
                      const ushort* __restrict__ A2, const ushort* __restrict__ Wt2,
                      const float* __restrict__ bias, ushort* __restrict__ C,
                      int rows, int K)
{
    constexpr int LDSP = 40;
    __shared__ __align__(16) ushort As[128 * LDSP];
    __shared__ __align__(16) ushort Bs[128 * LDSP];

    const int tid  = threadIdx.x;
    const int wave = tid >> 6;
    const int lane = tid & 63;
    const int quad = lane >> 4;
    const int l16  = lane & 15;
    const int wm   = (wave >> 1) * 64;   // wave row offset in tile
    const int wn   = (wave & 1) * 64;    // wave col offset in tile
    const int row0 = blockIdx.x * 128;
    const int n0   = blockIdx.y * 128;

    f32x4 acc[4][4];
#pragma unroll
    for (int i = 0; i < 4; ++i)
#pragma unroll
        for (int j = 0; j < 4; ++j)
#pragma unroll
            for (int r = 0; r < 4; ++r) acc[i][j][r] = 0.f;

    const int sr = tid >> 1;          // staging row 0..127
    const int sk = (tid & 1) * 16;    // staging k offset (elems)

    const int npass = DUAL ? 2 : 1;
    for (int pass = 0; pass < npass; ++pass) {
        const ushort* __restrict__ A = (DUAL && pass) ? A2 : A1;
        const ushort* __restrict__ W = (DUAL && pass) ? Wt2 : Wt1;

        for (int k0 = 0; k0 < K; k0 += 32) {
            // ---- stage A tile (128 rows x 32 k)
            {
                uint4 v0 = make_uint4(0, 0, 0, 0), v1 = make_uint4(0, 0, 0, 0);
                const int gr = row0 + sr;
                if (gr < rows) {
                    const uint4* src = (const uint4*)(A + (size_t)gr * K + k0 + sk);
                    v0 = src[0]; v1 = src[1];
                }
                *(uint4*)&As[sr * LDSP + sk]     = v0;
                *(uint4*)&As[sr * LDSP + sk + 8] = v1;
            }
            // ---- stage B tile (128 n x 32 k) from transposed weight
            {
                const uint4* src = (const uint4*)(W + (size_t)(n0 + sr) * K + k0 + sk);
                *(uint4*)&Bs[sr * LDSP + sk]     = src[0];
                *(uint4*)&Bs[sr * LDSP + sk + 8] = src[1];
            }
            __syncthreads();

            short8 af[4], bf[4];
#pragma unroll
            for (int t = 0; t < 4; ++t) {
                af[t] = *(const short8*)&As[(wm + t * 16 + l16) * LDSP + quad * 8];
                bf[t] = *(const short8*)&Bs[(wn + t * 16 + l16) * LDSP + quad * 8];
            }
#pragma unroll
            for (int tm = 0; tm < 4; ++tm)
#pragma unroll
                for (int tn = 0; tn < 4; ++tn)
                    acc[tm][tn] = __builtin_amdgcn_mfma_f32_16x16x32_bf16(
                        af[tm], bf[tn], acc[tm][tn], 0, 0, 0);
            __syncthreads();
        }
    }

    // ---- epilogue: bias + relu, bf16 store. C/D: row = quad*4+reg, col = l16
#pragma unroll
    for (int tm = 0; tm < 4; ++tm) {
        const int rbase = row0 + wm + tm * 16 + quad * 4;
#pragma unroll
        for (int reg = 0; reg < 4; ++reg) {
            const int grow = rbase + reg;
            if (grow < rows) {
#pragma unroll
                for (int tn = 0; tn < 4; ++tn) {
                    const int gcol = n0 + wn + tn * 16 + l16;
                    float v = acc[tm][tn][reg] + bias[gcol];
                    if (RELU) v = fmaxf(v, 0.f);
                    C[(size_t)grow * 256 + gcol] = f2b(v);
                }
            }
        }
    }
}

// ---------------------------------------------------------------------------
// Weight convert+transpose: Wt[n*K+k] = bf16(W[k*256+n]) (writes coalesced)
// ---------------------------------------------------------------------------
__global__ __launch_bounds__(256)
void wt_transpose_kernel(const float* __restrict__ W, ushort* __restrict__ Wt, int K)
{
    const int idx = blockIdx.x * 256 + threadIdx.x;
    if (idx < 256 * K) {
        const int n = idx / K;
        const int k = idx - n * K;
        Wt[idx] = f2b(W[k * 256 + n]);
    }
}

// x (fp32) -> bf16, 4 elems/thread
__global__ __launch_bounds__(256)
void cvt_bf16_kernel(const float* __restrict__ x, ushort* __restrict__ xb, int n4)
{
    const int i = blockIdx.x * 256 + threadIdx.x;
    if (i < n4) {
        const float4 v = ((const float4*)x)[i];
        ushort4 o;
        o.x = f2b(v.x); o.y = f2b(v.y); o.z = f2b(v.z); o.w = f2b(v.w);
        ((ushort4*)xb)[i] = o;
    }
}

// ---------------------------------------------------------------------------
// CSR build: count -> scan -> fill. edges laid out [bag][2][E], int32.
// ---------------------------------------------------------------------------
__global__ __launch_bounds__(256)
void count_kernel(const int* __restrict__ edges, int* __restrict__ cnt)
{
    const int e = blockIdx.x * 256 + threadIdx.x;
    const int b = blockIdx.y;
    if (e < NEDGES) {
        const int dst = edges[(size_t)b * 2 * NEDGES + NEDGES + e];
        atomicAdd(&cnt[b * NNODES + dst], 1);
    }
}

__global__ __launch_bounds__(1024)
void scan_kernel(const int* __restrict__ cnt, int* __restrict__ rowptr)
{
    const int b = blockIdx.x;
    const int t = threadIdx.x;
    __shared__ int sh[1024];
    const int CH = 5;
    const int base = t * CH;
    int local[CH];
    int sum = 0;
#pragma unroll
    for (int i = 0; i < CH; ++i) {
        const int g = base + i;
        const int v = (g < NNODES) ? cnt[b * NNODES + g] : 0;
        local[i] = v; sum += v;
    }
    sh[t] = sum;
    __syncthreads();
    for (int off = 1; off < 1024; off <<= 1) {
        const int add = (t >= off) ? sh[t - off] : 0;
        __syncthreads();
        sh[t] += add;
        __syncthreads();
    }
    int run = sh[t] - sum;
#pragma unroll
    for (int i = 0; i < CH; ++i) {
        const int g = base + i;
        if (g < NNODES) rowptr[b * (NNODES + 1) + g] = run;
        run += local[i];
    }
    if (t == 1023) rowptr[b * (NNODES + 1) + NNODES] = run;
}

__global__ __launch_bounds__(256)
void fill_kernel(const int* __restrict__ edges, const int* __restrict__ rowptr,
                 int* __restrict__ fillc, int* __restrict__ colidx)
{
    const int e = blockIdx.x * 256 + threadIdx.x;
    const int b = blockIdx.y;
    if (e < NEDGES) {
        const int* eb = edges + (size_t)b * 2 * NEDGES;
        const int src = eb[e];
        const int dst = eb[NEDGES + e];
        const int pos = rowptr[b * (NNODES + 1) + dst] + atomicAdd(&fillc[b * NNODES + dst], 1);
        colidx[(size_t)b * NEDGES + pos] = src;
    }
}

// ---------------------------------------------------------------------------
// Mean aggregation (pull), bf16 in/out, fp32 accumulate. 128 threads; thread d
// owns packed features (2d, 2d+1) -> 4 B/lane gathers (full coalescing/row).
// ---------------------------------------------------------------------------
__global__ __launch_bounds__(128)
void agg_mean_kernel(const ushort* __restrict__ X, const int* __restrict__ rowptr,
                     const int* __restrict__ colidx, ushort* __restrict__ M)
{
    const int node = blockIdx.x;
    const int b = blockIdx.y;
    const int d = threadIdx.x;     // 0..127
    const int* rp = rowptr + b * (NNODES + 1);
    int s = rp[node];
    const int e = rp[node + 1];
    const float inv = 1.0f / fmaxf((float)(e - s), 1.0f);
    const uint32_t* Xb = (const uint32_t*)(X + (size_t)b * NNODES * DENC);
    const int* ci = colidx + (size_t)b * NEDGES;
    __shared__ int idx[128];
    float a0 = 0.f, a1 = 0.f, a2 = 0.f, a3 = 0.f;
    while (s < e) {
        const int c = min(e - s, 128);
        __syncthreads();
        if (d < c) idx[d] = ci[s + d];
        __syncthreads();
        int j = 0;
        for (; j + 2 <= c; j += 2) {
            const uint32_t u0 = Xb[(size_t)idx[j] * 128 + d];
            const uint32_t u1 = Xb[(size_t)idx[j + 1] * 128 + d];
            a0 += __uint_as_float(u0 << 16);
            a1 += __uint_as_float(u0 & 0xffff0000u);
            a2 += __uint_as_float(u1 << 16);
            a3 += __uint_as_float(u1 & 0xffff0000u);
        }
        if (j < c) {
            const uint32_t u0 = Xb[(size_t)idx[j] * 128 + d];
            a0 += __uint_as_float(u0 << 16);
            a1 += __uint_as_float(u0 & 0xffff0000u);
        }
        s += c;
    }
    const ushort lo = f2b((a0 + a2) * inv);
    const ushort hi = f2b((a1 + a3) * inv);
    ((uint32_t*)M)[((size_t)b * NNODES + node) * 128 + d] = (uint32_t)lo | ((uint32_t)hi << 16);
}

// ---------------------------------------------------------------------------
// emb[bag] += partial column-sum of G2 (bf16) rows. emb fp32, zeroed before.
// ---------------------------------------------------------------------------
#define EMB_CHUNKS 40
__global__ __launch_bounds__(128)
void reduce_emb_kernel(const ushort* __restrict__ G2, float* __restrict__ emb, int bagBase)
{
    const int chunk = blockIdx.x;
    const int b = blockIdx.y;
    const int d = threadIdx.x;                 // packed feature pair
    const int n0 = chunk * (NNODES / EMB_CHUNKS);
    const int n1 = n0 + (NNODES / EMB_CHUNKS);
    const uint32_t* P = (const uint32_t*)G2 + ((size_t)b * NNODES + n0) * 128 + d;
    float a0 = 0.f, a1 = 0.f;
    for (int n = n0; n < n1; ++n) {
        const uint32_t u = *P;
        a0 += __uint_as_float(u << 16);
        a1 += __uint_as_float(u & 0xffff0000u);
        P += 128;
    }
    atomicAdd(&emb[(bagBase + b) * DENC + 2 * d], a0);
    atomicAdd(&emb[(bagBase + b) * DENC + 2 * d + 1], a1);
}

// ---------------------------------------------------------------------------
// classifier (fp32): out[b] = relu(emb[b]@Wc1 + bc1) @ Wc2 + bc2
// ---------------------------------------------------------------------------
__global__ __launch_bounds__(128)
void classifier_kernel(const float* __restrict__ emb, const float* __restrict__ Wc1,
                       const float* __restrict__ bc1, const float* __restrict__ Wc2,
                       const float* __restrict__ bc2, float* __restrict__ out)
{
    const int b = blockIdx.x;
    const int t = threadIdx.x;  // 128
    __shared__ float se[DENC];
    se[t] = emb[b * DENC + t];
    se[128 + t] = emb[b * DENC + 128 + t];
    __syncthreads();
    float h = bc1[t];
    for (int k = 0; k < DENC; ++k) h = fmaf(se[k], Wc1[k * DFC + t], h);
    h = fmaxf(h, 0.f);
    __shared__ float s0[128], s1[128];
    s0[t] = h * Wc2[t * NCLS + 0];
    s1[t] = h * Wc2[t * NCLS + 1];
    __syncthreads();
    for (int off = 64; off > 0; off >>= 1) {
        if (t < off) { s0[t] += s0[t + off]; s1[t] += s1[t + off]; }
        __syncthreads();
    }
    if (t == 0) {
        out[b * NCLS + 0] = s0[0] + bc2[0];
        out[b * NCLS + 1] = s1[0] + bc2[1];
    }
}

// ---------------------------------------------------------------------------
extern "C" void kernel_launch(void* const* d_in, const int* in_sizes, int n_in,
                              void* d_out, int out_size, void* d_ws, size_t ws_size,
                              hipStream_t stream)
{
    const float* x    = (const float*)d_in[0];
    const int*   edges= (const int*)d_in[1];   // int32 on device
    const float* We   = (const float*)d_in[2];
    const float* be   = (const float*)d_in[3];
    const float* Wl1  = (const float*)d_in[4];
    const float* bl1  = (const float*)d_in[5];
    const float* Wr1  = (const float*)d_in[6];
    const float* Wl2  = (const float*)d_in[7];
    const float* bl2  = (const float*)d_in[8];
    const float* Wr2  = (const float*)d_in[9];
    // d_in[10..12] = Wlp, blp, Wrp: dead (softmax over 1 cluster == 1)
    const float* Wc1  = (const float*)d_in[13];
    const float* bc1  = (const float*)d_in[14];
    const float* Wc2  = (const float*)d_in[15];
    const float* bc2  = (const float*)d_in[16];
    float* out = (float*)d_out;

    auto rnd = [](size_t v) { return (v + 255) & ~(size_t)255; };
    auto bytesFor = [&](int G) -> size_t {
        size_t tot = rnd((size_t)NBAGS * NNODES * DIN * 2);            // xb
        tot += 3 * rnd((size_t)G * NNODES * DENC * 2);                  // H, Mb, Gb
        tot += rnd((size_t)256 * DIN * 2) + 4 * rnd((size_t)256 * DENC * 2); // Wt
        tot += rnd((size_t)G * (NNODES + 1) * 4);                       // rowptr
        tot += 2 * rnd((size_t)G * NNODES * 4);                         // cnt, fill
        tot += rnd((size_t)G * NEDGES * 4);                             // colidx
        tot += rnd((size_t)NBAGS * DENC * 4);                           // emb
        return tot + 1024;
    };
    int G = NBAGS;
    while (G > 1 && bytesFor(G) > ws_size) G >>= 1;

    char* p = (char*)d_ws;
    auto alloc = [&](size_t bytes) -> char* {
        char* r = p; p += rnd(bytes); return r;
    };
    ushort* xb    = (ushort*)alloc((size_t)NBAGS * NNODES * DIN * 2);
    ushort* H     = (ushort*)alloc((size_t)G * NNODES * DENC * 2);  // h, then mean2
    ushort* Mb    = (ushort*)alloc((size_t)G * NNODES * DENC * 2);  // mean1, then g2
    ushort* Gb    = (ushort*)alloc((size_t)G * NNODES * DENC * 2);  // g1
    ushort* Wet   = (ushort*)alloc((size_t)256 * DIN * 2);
    ushort* Wl1t  = (ushort*)alloc((size_t)256 * DENC * 2);
    ushort* Wr1t  = (ushort*)alloc((size_t)256 * DENC * 2);
    ushort* Wl2t  = (ushort*)alloc((size_t)256 * DENC * 2);
    ushort* Wr2t  = (ushort*)alloc((size_t)256 * DENC * 2);
    int*    rowptr= (int*)   alloc((size_t)G * (NNODES + 1) * 4);
    int*    cnt   = (int*)   alloc((size_t)G * NNODES * 4);
    int*    fillc = (int*)   alloc((size_t)G * NNODES * 4);
    int*    colidx= (int*)   alloc((size_t)G * NEDGES * 4);
    float*  emb   = (float*) alloc((size_t)NBAGS * DENC * 4);

    // one-time per launch: conversions (ws re-poisoned each call)
    hipMemsetAsync(emb, 0, (size_t)NBAGS * DENC * 4, stream);
    {
        const int n4 = NBAGS * NNODES * DIN / 4;
        cvt_bf16_kernel<<<(n4 + 255) / 256, 256, 0, stream>>>(x, xb, n4);
        wt_transpose_kernel<<<(256 * DIN + 255) / 256, 256, 0, stream>>>(We, Wet, DIN);
        wt_transpose_kernel<<<(256 * DENC + 255) / 256, 256, 0, stream>>>(Wl1, Wl1t, DENC);
        wt_transpose_kernel<<<(256 * DENC + 255) / 256, 256, 0, stream>>>(Wr1, Wr1t, DENC);
        wt_transpose_kernel<<<(256 * DENC + 255) / 256, 256, 0, stream>>>(Wl2, Wl2t, DENC);
        wt_transpose_kernel<<<(256 * DENC + 255) / 256, 256, 0, stream>>>(Wr2, Wr2t, DENC);
    }

    for (int bagBase = 0; bagBase < NBAGS; bagBase += G) {
        const int g = (bagBase + G <= NBAGS) ? G : (NBAGS - bagBase);
        const int rows = g * NNODES;
        const ushort* xg = xb + (size_t)bagBase * NNODES * DIN;
        const int*    eg = edges + (size_t)bagBase * 2 * NEDGES;

        hipMemsetAsync(cnt,   0, (size_t)g * NNODES * 4, stream);
        hipMemsetAsync(fillc, 0, (size_t)g * NNODES * 4, stream);

        dim3 gemm_grid((rows + 127) / 128, 2);

        // encoder: H = relu(x @ We + be)
        gemm_bf16_kernel<false, true><<<gemm_grid, 256, 0, stream>>>(
            xg, Wet, nullptr, nullptr, be, H, rows, DIN);

        // CSR build (shared by both SAGE layers)
        count_kernel<<<dim3(NEDGES / 256, g), 256, 0, stream>>>(eg, cnt);
        scan_kernel<<<g, 1024, 0, stream>>>(cnt, rowptr);
        fill_kernel<<<dim3(NEDGES / 256, g), 256, 0, stream>>>(eg, rowptr, fillc, colidx);

        // layer 1: g1 = relu(mean1@Wl1 + h@Wr1 + bl1)
        agg_mean_kernel<<<dim3(NNODES, g), 128, 0, stream>>>(H, rowptr, colidx, Mb);
        gemm_bf16_kernel<true, true><<<gemm_grid, 256, 0, stream>>>(
            Mb, Wl1t, H, Wr1t, bl1, Gb, rows, DENC);

        // layer 2: g2 = relu(mean2@Wl2 + g1@Wr2 + bl2)  (mean2->H, g2->Mb)
        agg_mean_kernel<<<dim3(NNODES, g), 128, 0, stream>>>(Gb, rowptr, colidx, H);
        gemm_bf16_kernel<true, true><<<gemm_grid, 256, 0, stream>>>(
            H, Wl2t, Gb, Wr2t, bl2, Mb, rows, DENC);

        // emb[bag] += column-sums of g2
        reduce_emb_kernel<<<dim3(EMB_CHUNKS, g), 128, 0, stream>>>(Mb, emb, bagBase);
    }

    classifier_kernel<<<NBAGS, 128, 0, stream>>>(emb, Wc1, bc1, Wc2, bc2, out);
}

// Round 4
// 694.715 us; speedup vs baseline: 2.3320x; 1.1232x over previous
//
#include <hip/hip_runtime.h>
#include <hip/hip_bf16.h>
#include <cstdint>
#include <cstddef>

// Problem constants (from reference)
#define NBAGS  16
#define NNODES 5000
#define NEDGES 160000
#define DIN    128
#define DENC   256   // == D_GNN
#define DFC    128
#define NCLS   2

typedef __attribute__((ext_vector_type(8))) short short8;
typedef __attribute__((ext_vector_type(4))) float f32x4;

static __device__ __forceinline__ ushort f2b(float v) {
    __hip_bfloat16 b = __float2bfloat16(v);   // RNE
    return *reinterpret_cast<ushort*>(&b);
}

// ---------------------------------------------------------------------------
// bf16 MFMA GEMM: C[rows x 256] = act( A1@W1t^T (+ A2@W2t^T) + bias )
// REDUCE=true: instead of storing C, column-sum relu(rows) into emb[bag][col]
// (bag-straddle handled; used by the final SAGE layer whose output is only
// ever column-summed -> g2 never materialized).
// BM=BN=128, BK=32, 256 threads = 4 waves (2x2), wave tile 64x64 via 4x4
// mfma_f32_16x16x32_bf16. LDS rows padded to 40 elems: b128 reads 2-way free.
// ---------------------------------------------------------------------------
template<bool DUAL, bool RELU, bool REDUCE>
__global__ __launch_bounds__(256)
void gemm_bf16_kernel(const ushort* __restrict__ A1, const ushort* __restrict__ Wt1,
                      const ushort* __restrict__ A2, const ushort* __restrict__ Wt2,
                      const float* __restrict__ bias, ushort* __restrict__ C,
                      float* __restrict__ emb, int rows, int K, int bagBase, int g)
{
    constexpr int LDSP = 40;
    __shared__ __align__(16) ushort As[128 * LDSP];
    __shared__ __align__(16) ushort Bs[128 * LDSP];

    const int tid  = threadIdx.x;
    const int wave = tid >> 6;
    const int lane = tid & 63;
    const int quad = lane >> 4;
    const int l16  = lane & 15;
    const int wm   = (wave >> 1) * 64;
    const int wn   = (wave & 1) * 64;
    const int row0 = blockIdx.x * 128;
    const int n0   = blockIdx.y * 128;

    f32x4 acc[4][4];
#pragma unroll
    for (int i = 0; i < 4; ++i)
#pragma unroll
        for (int j = 0; j < 4; ++j)
#pragma unroll
            for (int r = 0; r < 4; ++r) acc[i][j][r] = 0.f;

    const int sr = tid >> 1;
    const int sk = (tid & 1) * 16;

    const int npass = DUAL ? 2 : 1;
    for (int pass = 0; pass < npass; ++pass) {
        const ushort* __restrict__ A = (DUAL && pass) ? A2 : A1;
        const ushort* __restrict__ W = (DUAL && pass) ? Wt2 : Wt1;

        for (int k0 = 0; k0 < K; k0 += 32) {
            {
                uint4 v0 = make_uint4(0, 0, 0, 0), v1 = make_uint4(0, 0, 0, 0);
                const int gr = row0 + sr;
                if (gr < rows) {
                    const uint4* src = (const uint4*)(A + (size_t)gr * K + k0 + sk);
                    v0 = src[0]; v1 = src[1];
                }
                *(uint4*)&As[sr * LDSP + sk]     = v0;
                *(uint4*)&As[sr * LDSP + sk + 8] = v1;
            }
            {
                const uint4* src = (const uint4*)(W + (size_t)(n0 + sr) * K + k0 + sk);
                *(uint4*)&Bs[sr * LDSP + sk]     = src[0];
                *(uint4*)&Bs[sr * LDSP + sk + 8] = src[1];
            }
            __syncthreads();

            short8 af[4], bf[4];
#pragma unroll
            for (int t = 0; t < 4; ++t) {
                af[t] = *(const short8*)&As[(wm + t * 16 + l16) * LDSP + quad * 8];
                bf[t] = *(const short8*)&Bs[(wn + t * 16 + l16) * LDSP + quad * 8];
            }
#pragma unroll
            for (int tm = 0; tm < 4; ++tm)
#pragma unroll
                for (int tn = 0; tn < 4; ++tn)
                    acc[tm][tn] = __builtin_amdgcn_mfma_f32_16x16x32_bf16(
                        af[tm], bf[tn], acc[tm][tn], 0, 0, 0);
            __syncthreads();
        }
    }

    if (!REDUCE) {
        // epilogue: bias + relu, bf16 store. C/D: row = quad*4+reg, col = l16
#pragma unroll
        for (int tm = 0; tm < 4; ++tm) {
            const int rbase = row0 + wm + tm * 16 + quad * 4;
#pragma unroll
            for (int reg = 0; reg < 4; ++reg) {
                const int grow = rbase + reg;
                if (grow < rows) {
#pragma unroll
                    for (int tn = 0; tn < 4; ++tn) {
                        const int gcol = n0 + wn + tn * 16 + l16;
                        float v = acc[tm][tn][reg] + bias[gcol];
                        if (RELU) v = fmaxf(v, 0.f);
                        C[(size_t)grow * 256 + gcol] = f2b(v);
                    }
                }
            }
        }
    } else {
        // fused column-sum epilogue -> emb (block may straddle 2 bags)
        __shared__ float red[2][128];
        ((float*)red)[tid] = 0.f;
        __syncthreads();
        const int bagA = row0 / NNODES;
        const int boundary = (bagA + 1) * NNODES;
#pragma unroll
        for (int tn = 0; tn < 4; ++tn) {
            const int cl = wn + tn * 16 + l16;            // col within tile
            const float bv = bias[n0 + cl];
            float p0 = 0.f, p1 = 0.f;
#pragma unroll
            for (int tm = 0; tm < 4; ++tm) {
#pragma unroll
                for (int reg = 0; reg < 4; ++reg) {
                    const int grow = row0 + wm + tm * 16 + quad * 4 + reg;
                    float v = acc[tm][tn][reg] + bv;
                    if (RELU) v = fmaxf(v, 0.f);
                    if (grow < rows) {
                        if (grow >= boundary) p1 += v; else p0 += v;
                    }
                }
            }
            atomicAdd(&red[0][cl], p0);
            atomicAdd(&red[1][cl], p1);
        }
        __syncthreads();
        {
            const int slot = tid >> 7;
            const int col  = tid & 127;
            const int bag  = bagA + slot;
            if (bag < g)
                atomicAdd(&emb[(bagBase + bag) * DENC + n0 + col], red[slot][col]);
        }
    }
}

// ---------------------------------------------------------------------------
// Weight convert+transpose: Wt[n*K+k] = bf16(W[k*256+n])
// ---------------------------------------------------------------------------
__global__ __launch_bounds__(256)
void wt_transpose_kernel(const float* __restrict__ W, ushort* __restrict__ Wt, int K)
{
    const int idx = blockIdx.x * 256 + threadIdx.x;
    if (idx < 256 * K) {
        const int n = idx / K;
        const int k = idx - n * K;
        Wt[idx] = f2b(W[k * 256 + n]);
    }
}

__global__ __launch_bounds__(256)
void cvt_bf16_kernel(const float* __restrict__ x, ushort* __restrict__ xb, int n4)
{
    const int i = blockIdx.x * 256 + threadIdx.x;
    if (i < n4) {
        const float4 v = ((const float4*)x)[i];
        ushort4 o;
        o.x = f2b(v.x); o.y = f2b(v.y); o.z = f2b(v.z); o.w = f2b(v.w);
        ((ushort4*)xb)[i] = o;
    }
}

// ---------------------------------------------------------------------------
// CSR build: count -> scan -> fill. edges laid out [bag][2][E], int32.
// ---------------------------------------------------------------------------
__global__ __launch_bounds__(256)
void count_kernel(const int* __restrict__ edges, int* __restrict__ cnt)
{
    const int e = blockIdx.x * 256 + threadIdx.x;
    const int b = blockIdx.y;
    if (e < NEDGES) {
        const int dst = edges[(size_t)b * 2 * NEDGES + NEDGES + e];
        atomicAdd(&cnt[b * NNODES + dst], 1);
    }
}

__global__ __launch_bounds__(1024)
void scan_kernel(const int* __restrict__ cnt, int* __restrict__ rowptr)
{
    const int b = blockIdx.x;
    const int t = threadIdx.x;
    __shared__ int sh[1024];
    const int CH = 5;
    const int base = t * CH;
    int local[CH];
    int sum = 0;
#pragma unroll
    for (int i = 0; i < CH; ++i) {
        const int g = base + i;
        const int v = (g < NNODES) ? cnt[b * NNODES + g] : 0;
        local[i] = v; sum += v;
    }
    sh[t] = sum;
    __syncthreads();
    for (int off = 1; off < 1024; off <<= 1) {
        const int add = (t >= off) ? sh[t - off] : 0;
        __syncthreads();
        sh[t] += add;
        __syncthreads();
    }
    int run = sh[t] - sum;
#pragma unroll
    for (int i = 0; i < CH; ++i) {
        const int g = base + i;
        if (g < NNODES) rowptr[b * (NNODES + 1) + g] = run;
        run += local[i];
    }
    if (t == 1023) rowptr[b * (NNODES + 1) + NNODES] = run;
}

__global__ __launch_bounds__(256)
void fill_kernel(const int* __restrict__ edges, const int* __restrict__ rowptr,
                 int* __restrict__ fillc, int* __restrict__ colidx)
{
    const int e = blockIdx.x * 256 + threadIdx.x;
    const int b = blockIdx.y;
    if (e < NEDGES) {
        const int* eb = edges + (size_t)b * 2 * NEDGES;
        const int src = eb[e];
        const int dst = eb[NEDGES + e];
        const int pos = rowptr[b * (NNODES + 1) + dst] + atomicAdd(&fillc[b * NNODES + dst], 1);
        colidx[(size_t)b * NEDGES + pos] = src;
    }
}

// ---------------------------------------------------------------------------
// Mean aggregation (pull), bf16 in/out, fp32 accumulate.
// One WAVE per node: 64 lanes x uint2 = 512 B = one full feature row per vmem
// instr. Neighbor indices are wave-uniform -> scalar loads, no LDS/barriers.
// 1-D grid with XCD swizzle: bag = blockIdx%8 (+8 second half) so each XCD's
// L2 holds ~one bag's 2.56 MB feature matrix.
// ---------------------------------------------------------------------------
__global__ __launch_bounds__(256)
void agg_mean_kernel(const ushort* __restrict__ X, const int* __restrict__ rowptr,
                     const int* __restrict__ colidx, ushort* __restrict__ M, int g)
{
    constexpr int GPB = NNODES / 4;   // node-groups per bag (4 waves/block)
    const int bx = blockIdx.x;
    int bag, grp;
    if (g == NBAGS) {
        const int half = 8 * GPB;
        const int hi = (bx >= half) ? 1 : 0;
        const int r = bx - hi * half;
        bag = (r & 7) + hi * 8;
        grp = r >> 3;
    } else {
        bag = bx / GPB;
        grp = bx - bag * GPB;
    }
    const int wave = threadIdx.x >> 6;
    const int lane = threadIdx.x & 63;
    const int node = grp * 4 + wave;

    const int* rp = rowptr + bag * (NNODES + 1);
    int s = rp[node];
    const int e = rp[node + 1];
    const float inv = 1.0f / fmaxf((float)(e - s), 1.0f);
    const uint2* __restrict__ Xb = (const uint2*)(X + (size_t)bag * NNODES * DENC);
    const int* __restrict__ ci = colidx + (size_t)bag * NEDGES;

    float a0 = 0.f, a1 = 0.f, a2 = 0.f, a3 = 0.f;
    int j = s;
    for (; j + 4 <= e; j += 4) {
        const int i0 = ci[j], i1 = ci[j + 1], i2 = ci[j + 2], i3 = ci[j + 3];
        const uint2 u0 = Xb[i0 * 64 + lane];
        const uint2 u1 = Xb[i1 * 64 + lane];
        const uint2 u2 = Xb[i2 * 64 + lane];
        const uint2 u3 = Xb[i3 * 64 + lane];
        a0 += __uint_as_float(u0.x << 16); a1 += __uint_as_float(u0.x & 0xffff0000u);
        a2 += __uint_as_float(u0.y << 16); a3 += __uint_as_float(u0.y & 0xffff0000u);
        a0 += __uint_as_float(u1.x << 16); a1 += __uint_as_float(u1.x & 0xffff0000u);
        a2 += __uint_as_float(u1.y << 16); a3 += __uint_as_float(u1.y & 0xffff0000u);
        a0 += __uint_as_float(u2.x << 16); a1 += __uint_as_float(u2.x & 0xffff0000u);
        a2 += __uint_as_float(u2.y << 16); a3 += __uint_as_float(u2.y & 0xffff0000u);
        a0 += __uint_as_float(u3.x << 16); a1 += __uint_as_float(u3.x & 0xffff0000u);
        a2 += __uint_as_float(u3.y << 16); a3 += __uint_as_float(u3.y & 0xffff0000u);
    }
    for (; j < e; ++j) {
        const uint2 u = Xb[ci[j] * 64 + lane];
        a0 += __uint_as_float(u.x << 16); a1 += __uint_as_float(u.x & 0xffff0000u);
        a2 += __uint_as_float(u.y << 16); a3 += __uint_as_float(u.y & 0xffff0000u);
    }
    uint2 o;
    o.x = (uint32_t)f2b(a0 * inv) | ((uint32_t)f2b(a1 * inv) << 16);
    o.y = (uint32_t)f2b(a2 * inv) | ((uint32_t)f2b(a3 * inv) << 16);
    ((uint2*)(M + ((size_t)bag * NNODES + node) * DENC))[lane] = o;
}

// ---------------------------------------------------------------------------
// classifier (fp32): out[b] = relu(emb[b]@Wc1 + bc1) @ Wc2 + bc2
// ---------------------------------------------------------------------------
__global__ __launch_bounds__(128)
void classifier_kernel(const float* __restrict__ emb, const float* __restrict__ Wc1,
                       const float* __restrict__ bc1, const float* __restrict__ Wc2,
                       const float* __restrict__ bc2, float* __restrict__ out)
{
    const int b = blockIdx.x;
    const int t = threadIdx.x;  // 128
    __shared__ float se[DENC];
    se[t] = emb[b * DENC + t];
    se[128 + t] = emb[b * DENC + 128 + t];
    __syncthreads();
    float h = bc1[t];
    for (int k = 0; k < DENC; ++k) h = fmaf(se[k], Wc1[k * DFC + t], h);
    h = fmaxf(h, 0.f);
    __shared__ float s0[128], s1[128];
    s0[t] = h * Wc2[t * NCLS + 0];
    s1[t] = h * Wc2[t * NCLS + 1];
    __syncthreads();
    for (int off = 64; off > 0; off >>= 1) {
        if (t < off) { s0[t] += s0[t + off]; s1[t] += s1[t + off]; }
        __syncthreads();
    }
    if (t == 0) {
        out[b * NCLS + 0] = s0[0] + bc2[0];
        out[b * NCLS + 1] = s1[0] + bc2[1];
    }
}

// ---------------------------------------------------------------------------
extern "C" void kernel_launch(void* const* d_in, const int* in_sizes, int n_in,
                              void* d_out, int out_size, void* d_ws, size_t ws_size,
                              hipStream_t stream)
{
    const float* x    = (const float*)d_in[0];
    const int*   edges= (const int*)d_in[1];   // int32 on device
    const float* We   = (const float*)d_in[2];
    const float* be   = (const float*)d_in[3];
    const float* Wl1  = (const float*)d_in[4];
    const float* bl1  = (const float*)d_in[5];
    const float* Wr1  = (const float*)d_in[6];
    const float* Wl2  = (const float*)d_in[7];
    const float* bl2  = (const float*)d_in[8];
    const float* Wr2  = (const float*)d_in[9];
    // d_in[10..12] = Wlp, blp, Wrp: dead (softmax over 1 cluster == 1)
    const float* Wc1  = (const float*)d_in[13];
    const float* bc1  = (const float*)d_in[14];
    const float* Wc2  = (const float*)d_in[15];
    const float* bc2  = (const float*)d_in[16];
    float* out = (float*)d_out;

    auto rnd = [](size_t v) { return (v + 255) & ~(size_t)255; };
    auto bytesFor = [&](int G) -> size_t {
        size_t tot = rnd((size_t)NBAGS * NNODES * DIN * 2);            // xb
        tot += 3 * rnd((size_t)G * NNODES * DENC * 2);                  // H, Mb, Gb
        tot += rnd((size_t)256 * DIN * 2) + 4 * rnd((size_t)256 * DENC * 2); // Wt
        tot += rnd((size_t)G * (NNODES + 1) * 4);                       // rowptr
        tot += 2 * rnd((size_t)G * NNODES * 4);                         // cnt, fill
        tot += rnd((size_t)G * NEDGES * 4);                             // colidx
        tot += rnd((size_t)NBAGS * DENC * 4);                           // emb
        return tot + 1024;
    };
    int G = NBAGS;
    while (G > 1 && bytesFor(G) > ws_size) G >>= 1;

    char* p = (char*)d_ws;
    auto alloc = [&](size_t bytes) -> char* {
        char* r = p; p += rnd(bytes); return r;
    };
    ushort* xb    = (ushort*)alloc((size_t)NBAGS * NNODES * DIN * 2);
    ushort* H     = (ushort*)alloc((size_t)G * NNODES * DENC * 2);  // h, then mean2
    ushort* Mb    = (ushort*)alloc((size_t)G * NNODES * DENC * 2);  // mean1
    ushort* Gb    = (ushort*)alloc((size_t)G * NNODES * DENC * 2);  // g1
    ushort* Wet   = (ushort*)alloc((size_t)256 * DIN * 2);
    ushort* Wl1t  = (ushort*)alloc((size_t)256 * DENC * 2);
    ushort* Wr1t  = (ushort*)alloc((size_t)256 * DENC * 2);
    ushort* Wl2t  = (ushort*)alloc((size_t)256 * DENC * 2);
    ushort* Wr2t  = (ushort*)alloc((size_t)256 * DENC * 2);
    int*    rowptr= (int*)   alloc((size_t)G * (NNODES + 1) * 4);
    int*    cnt   = (int*)   alloc((size_t)G * NNODES * 4);
    int*    fillc = (int*)   alloc((size_t)G * NNODES * 4);
    int*    colidx= (int*)   alloc((size_t)G * NEDGES * 4);
    float*  emb   = (float*) alloc((size_t)NBAGS * DENC * 4);

    // one-time per launch: conversions (ws re-poisoned each call)
    hipMemsetAsync(emb, 0, (size_t)NBAGS * DENC * 4, stream);
    {
        const int n4 = NBAGS * NNODES * DIN / 4;
        cvt_bf16_kernel<<<(n4 + 255) / 256, 256, 0, stream>>>(x, xb, n4);
        wt_transpose_kernel<<<(256 * DIN + 255) / 256, 256, 0, stream>>>(We, Wet, DIN);
        wt_transpose_kernel<<<(256 * DENC + 255) / 256, 256, 0, stream>>>(Wl1, Wl1t, DENC);
        wt_transpose_kernel<<<(256 * DENC + 255) / 256, 256, 0, stream>>>(Wr1, Wr1t, DENC);
        wt_transpose_kernel<<<(256 * DENC + 255) / 256, 256, 0, stream>>>(Wl2, Wl2t, DENC);
        wt_transpose_kernel<<<(256 * DENC + 255) / 256, 256, 0, stream>>>(Wr2, Wr2t, DENC);
    }

    for (int bagBase = 0; bagBase < NBAGS; bagBase += G) {
        const int g = (bagBase + G <= NBAGS) ? G : (NBAGS - bagBase);
        const int rows = g * NNODES;
        const ushort* xg = xb + (size_t)bagBase * NNODES * DIN;
        const int*    eg = edges + (size_t)bagBase * 2 * NEDGES;

        hipMemsetAsync(cnt,   0, (size_t)g * NNODES * 4, stream);
        hipMemsetAsync(fillc, 0, (size_t)g * NNODES * 4, stream);

        dim3 gemm_grid((rows + 127) / 128, 2);
        const int agg_blocks = g * (NNODES / 4);

        // encoder: H = relu(x @ We + be)
        gemm_bf16_kernel<false, true, false><<<gemm_grid, 256, 0, stream>>>(
            xg, Wet, nullptr, nullptr, be, H, nullptr, rows, DIN, bagBase, g);

        // CSR build (shared by both SAGE layers)
        count_kernel<<<dim3(NEDGES / 256, g), 256, 0, stream>>>(eg, cnt);
        scan_kernel<<<g, 1024, 0, stream>>>(cnt, rowptr);
        fill_kernel<<<dim3(NEDGES / 256, g), 256, 0, stream>>>(eg, rowptr, fillc, colidx);

        // layer 1: g1 = relu(mean1@Wl1 + h@Wr1 + bl1)
        agg_mean_kernel<<<agg_blocks, 256, 0, stream>>>(H, rowptr, colidx, Mb, g);
        gemm_bf16_kernel<true, true, false><<<gemm_grid, 256, 0, stream>>>(
            Mb, Wl1t, H, Wr1t, bl1, Gb, nullptr, rows, DENC, bagBase, g);

        // layer 2 fused with emb reduction: emb[bag] += relu(mean2@Wl2 + g1@Wr2 + bl2)
        agg_mean_kernel<<<agg_blocks, 256, 0, stream>>>(Gb, rowptr, colidx, H, g);
        gemm_bf16_kernel<true, true, true><<<gemm_grid, 256, 0, stream>>>(
            H, Wl2t, Gb, Wr2t, bl2, nullptr, emb, rows, DENC, bagBase, g);
    }

    classifier_kernel<<<NBAGS, 128, 0, stream>>>(emb, Wc1, bc1, Wc2, bc2, out);
}

// Round 5
// 666.591 us; speedup vs baseline: 2.4304x; 1.0422x over previous
//
#include <hip/hip_runtime.h>
#include <hip/hip_bf16.h>
#include <cstdint>
#include <cstddef>

// Problem constants (from reference)
#define NBAGS  16
#define NNODES 5000
#define NEDGES 160000
#define DIN    128
#define DENC   256   // == D_GNN
#define DFC    128
#define NCLS   2

typedef __attribute__((ext_vector_type(8))) short short8;
typedef __attribute__((ext_vector_type(4))) float f32x4;

static __device__ __forceinline__ ushort f2b(float v) {
    __hip_bfloat16 b = __float2bfloat16(v);   // RNE
    return *reinterpret_cast<ushort*>(&b);
}

// ---------------------------------------------------------------------------
// bf16 MFMA GEMM: C[rows x 256] = act( A1@W1t^T (+ A2@W2t^T) + bias )
// REDUCE=true: column-sum relu(rows) into emb[bag][col] instead of storing C.
// BM=BN=128, BK=32, 256 threads = 4 waves (2x2), wave tile 64x64 via 4x4
// mfma_f32_16x16x32_bf16. LDS rows padded to 40 elems: b128 reads 2-way free.
// ---------------------------------------------------------------------------
template<bool DUAL, bool RELU, bool REDUCE>
__global__ __launch_bounds__(256)
void gemm_bf16_kernel(const ushort* __restrict__ A1, const ushort* __restrict__ Wt1,
                      const ushort* __restrict__ A2, const ushort* __restrict__ Wt2,
                      const float* __restrict__ bias, ushort* __restrict__ C,
                      float* __restrict__ emb, int rows, int K, int bagBase, int g)
{
    constexpr int LDSP = 40;
    __shared__ __align__(16) ushort As[128 * LDSP];
    __shared__ __align__(16) ushort Bs[128 * LDSP];

    const int tid  = threadIdx.x;
    const int wave = tid >> 6;
    const int lane = tid & 63;
    const int quad = lane >> 4;
    const int l16  = lane & 15;
    const int wm   = (wave >> 1) * 64;
    const int wn   = (wave & 1) * 64;
    const int row0 = blockIdx.x * 128;
    const int n0   = blockIdx.y * 128;

    f32x4 acc[4][4];
#pragma unroll
    for (int i = 0; i < 4; ++i)
#pragma unroll
        for (int j = 0; j < 4; ++j)
#pragma unroll
            for (int r = 0; r < 4; ++r) acc[i][j][r] = 0.f;

    const int sr = tid >> 1;
    const int sk = (tid & 1) * 16;

    const int npass = DUAL ? 2 : 1;
    for (int pass = 0; pass < npass; ++pass) {
        const ushort* __restrict__ A = (DUAL && pass) ? A2 : A1;
        const ushort* __restrict__ W = (DUAL && pass) ? Wt2 : Wt1;

        for (int k0 = 0; k0 < K; k0 += 32) {
            {
                uint4 v0 = make_uint4(0, 0, 0, 0), v1 = make_uint4(0, 0, 0, 0);
                const int gr = row0 + sr;
                if (gr < rows) {
                    const uint4* src = (const uint4*)(A + (size_t)gr * K + k0 + sk);
                    v0 = src[0]; v1 = src[1];
                }
                *(uint4*)&As[sr * LDSP + sk]     = v0;
                *(uint4*)&As[sr * LDSP + sk + 8] = v1;
            }
            {
                const uint4* src = (const uint4*)(W + (size_t)(n0 + sr) * K + k0 + sk);
                *(uint4*)&Bs[sr * LDSP + sk]     = src[0];
                *(uint4*)&Bs[sr * LDSP + sk + 8] = src[1];
            }
            __syncthreads();

            short8 af[4], bf[4];
#pragma unroll
            for (int t = 0; t < 4; ++t) {
                af[t] = *(const short8*)&As[(wm + t * 16 + l16) * LDSP + quad * 8];
                bf[t] = *(const short8*)&Bs[(wn + t * 16 + l16) * LDSP + quad * 8];
            }
#pragma unroll
            for (int tm = 0; tm < 4; ++tm)
#pragma unroll
                for (int tn = 0; tn < 4; ++tn)
                    acc[tm][tn] = __builtin_amdgcn_mfma_f32_16x16x32_bf16(
                        af[tm], bf[tn], acc[tm][tn], 0, 0, 0);
            __syncthreads();
        }
    }

    if (!REDUCE) {
        // epilogue: bias + relu, bf16 store. C/D: row = quad*4+reg, col = l16
#pragma unroll
        for (int tm = 0; tm < 4; ++tm) {
            const int rbase = row0 + wm + tm * 16 + quad * 4;
#pragma unroll
            for (int reg = 0; reg < 4; ++reg) {
                const int grow = rbase + reg;
                if (grow < rows) {
#pragma unroll
                    for (int tn = 0; tn < 4; ++tn) {
                        const int gcol = n0 + wn + tn * 16 + l16;
                        float v = acc[tm][tn][reg] + bias[gcol];
                        if (RELU) v = fmaxf(v, 0.f);
                        C[(size_t)grow * 256 + gcol] = f2b(v);
                    }
                }
            }
        }
    } else {
        // fused column-sum epilogue -> emb (block may straddle 2 bags)
        __shared__ float red[2][128];
        ((float*)red)[tid] = 0.f;
        __syncthreads();
        const int bagA = row0 / NNODES;
        const int boundary = (bagA + 1) * NNODES;
#pragma unroll
        for (int tn = 0; tn < 4; ++tn) {
            const int cl = wn + tn * 16 + l16;            // col within tile
            const float bv = bias[n0 + cl];
            float p0 = 0.f, p1 = 0.f;
#pragma unroll
            for (int tm = 0; tm < 4; ++tm) {
#pragma unroll
                for (int reg = 0; reg < 4; ++reg) {
                    const int grow = row0 + wm + tm * 16 + quad * 4 + reg;
                    float v = acc[tm][tn][reg] + bv;
                    if (RELU) v = fmaxf(v, 0.f);
                    if (grow < rows) {
                        if (grow >= boundary) p1 += v; else p0 += v;
                    }
                }
            }
            atomicAdd(&red[0][cl], p0);
            atomicAdd(&red[1][cl], p1);
        }
        __syncthreads();
        {
            const int slot = tid >> 7;
            const int col  = tid & 127;
            const int bag  = bagA + slot;
            if (bag < g)
                atomicAdd(&emb[(bagBase + bag) * DENC + n0 + col], red[slot][col]);
        }
    }
}

// ---------------------------------------------------------------------------
// Weight convert+transpose: Wt[n*K+k] = bf16(W[k*256+n])
// ---------------------------------------------------------------------------
__global__ __launch_bounds__(256)
void wt_transpose_kernel(const float* __restrict__ W, ushort* __restrict__ Wt, int K)
{
    const int idx = blockIdx.x * 256 + threadIdx.x;
    if (idx < 256 * K) {
        const int n = idx / K;
        const int k = idx - n * K;
        Wt[idx] = f2b(W[k * 256 + n]);
    }
}

__global__ __launch_bounds__(256)
void cvt_bf16_kernel(const float* __restrict__ x, ushort* __restrict__ xb, int n4)
{
    const int i = blockIdx.x * 256 + threadIdx.x;
    if (i < n4) {
        const float4 v = ((const float4*)x)[i];
        ushort4 o;
        o.x = f2b(v.x); o.y = f2b(v.y); o.z = f2b(v.z); o.w = f2b(v.w);
        ((ushort4*)xb)[i] = o;
    }
}

// ---------------------------------------------------------------------------
// CSR build: count -> scan -> fill. edges laid out [bag][2][E], int32.
// count/fill use bag->XCD swizzle (bag = blockIdx%8 within each half) so each
// bag's cnt/fillc/colidx lines live in ONE XCD's L2: full lines assembled
// before writeback (kills the 12x partial-line write amplification) and
// atomics stay L2-local. 4 edges/thread for MLP on the atomic->store chain.
// ---------------------------------------------------------------------------
#define CSR_EPB 1024                         // edges per block
#define CSR_BPB ((NEDGES + CSR_EPB - 1) / CSR_EPB)   // 157 blocks per bag

static __device__ __forceinline__ void bag_chunk(int bx, int g, int bpb, int& bag, int& chunk)
{
    if (g == NBAGS) {
        const int half = 8 * bpb;
        const int hi = (bx >= half) ? 1 : 0;
        const int r = bx - hi * half;
        bag = (r & 7) + hi * 8;
        chunk = r >> 3;
    } else {
        bag = bx / bpb;
        chunk = bx - bag * bpb;
    }
}

__global__ __launch_bounds__(256)
void count_kernel(const int* __restrict__ edges, int* __restrict__ cnt, int g)
{
    int bag, chunk;
    bag_chunk(blockIdx.x, g, CSR_BPB, bag, chunk);
    const int* __restrict__ dstp = edges + (size_t)bag * 2 * NEDGES + NEDGES;
    int* __restrict__ cb = cnt + bag * NNODES;
    const int e0 = chunk * CSR_EPB + threadIdx.x;
    int d[4];
#pragma unroll
    for (int i = 0; i < 4; ++i) {
        const int e = e0 + i * 256;
        d[i] = (e < NEDGES) ? dstp[e] : -1;
    }
#pragma unroll
    for (int i = 0; i < 4; ++i)
        if (d[i] >= 0) atomicAdd(&cb[d[i]], 1);
}

__global__ __launch_bounds__(1024)
void scan_kernel(const int* __restrict__ cnt, int* __restrict__ rowptr)
{
    const int b = blockIdx.x;
    const int t = threadIdx.x;
    __shared__ int sh[1024];
    const int CH = 5;
    const int base = t * CH;
    int local[CH];
    int sum = 0;
#pragma unroll
    for (int i = 0; i < CH; ++i) {
        const int g = base + i;
        const int v = (g < NNODES) ? cnt[b * NNODES + g] : 0;
        local[i] = v; sum += v;
    }
    sh[t] = sum;
    __syncthreads();
    for (int off = 1; off < 1024; off <<= 1) {
        const int add = (t >= off) ? sh[t - off] : 0;
        __syncthreads();
        sh[t] += add;
        __syncthreads();
    }
    int run = sh[t] - sum;
#pragma unroll
    for (int i = 0; i < CH; ++i) {
        const int g = base + i;
        if (g < NNODES) rowptr[b * (NNODES + 1) + g] = run;
        run += local[i];
    }
    if (t == 1023) rowptr[b * (NNODES + 1) + NNODES] = run;
}

__global__ __launch_bounds__(256)
void fill_kernel(const int* __restrict__ edges, const int* __restrict__ rowptr,
                 int* __restrict__ fillc, int* __restrict__ colidx, int g)
{
    int bag, chunk;
    bag_chunk(blockIdx.x, g, CSR_BPB, bag, chunk);
    const int* __restrict__ eb = edges + (size_t)bag * 2 * NEDGES;
    const int* __restrict__ rp = rowptr + bag * (NNODES + 1);
    int* __restrict__ fc = fillc + bag * NNODES;
    int* __restrict__ co = colidx + (size_t)bag * NEDGES;
    const int e0 = chunk * CSR_EPB + threadIdx.x;
    int src[4], dst[4];
#pragma unroll
    for (int i = 0; i < 4; ++i) {
        const int e = e0 + i * 256;
        if (e < NEDGES) { src[i] = eb[e]; dst[i] = eb[NEDGES + e]; }
        else dst[i] = -1;
    }
#pragma unroll
    for (int i = 0; i < 4; ++i) {
        if (dst[i] >= 0) {
            const int pos = rp[dst[i]] + atomicAdd(&fc[dst[i]], 1);
            co[pos] = src[i];
        }
    }
}

// ---------------------------------------------------------------------------
// Mean aggregation (pull), bf16 in/out, fp32 accumulate.
// One WAVE per node: 64 lanes x uint2 = 512 B = one full feature row per vmem
// instr. Wave-uniform neighbor indices -> scalar loads, no LDS/barriers.
// bag->XCD swizzle keeps each bag's 2.56 MB feature matrix in one L2.
// ---------------------------------------------------------------------------
__global__ __launch_bounds__(256)
void agg_mean_kernel(const ushort* __restrict__ X, const int* __restrict__ rowptr,
                     const int* __restrict__ colidx, ushort* __restrict__ M, int g)
{
    constexpr int GPB = NNODES / 4;   // node-groups per bag (4 waves/block)
    int bag, grp;
    bag_chunk(blockIdx.x, g, GPB, bag, grp);
    const int wave = threadIdx.x >> 6;
    const int lane = threadIdx.x & 63;
    const int node = grp * 4 + wave;

    const int* rp = rowptr + bag * (NNODES + 1);
    int s = rp[node];
    const int e = rp[node + 1];
    const float inv = 1.0f / fmaxf((float)(e - s), 1.0f);
    const uint2* __restrict__ Xb = (const uint2*)(X + (size_t)bag * NNODES * DENC);
    const int* __restrict__ ci = colidx + (size_t)bag * NEDGES;

    float a0 = 0.f, a1 = 0.f, a2 = 0.f, a3 = 0.f;
    int j = s;
    for (; j + 4 <= e; j += 4) {
        const int i0 = ci[j], i1 = ci[j + 1], i2 = ci[j + 2], i3 = ci[j + 3];
        const uint2 u0 = Xb[i0 * 64 + lane];
        const uint2 u1 = Xb[i1 * 64 + lane];
        const uint2 u2 = Xb[i2 * 64 + lane];
        const uint2 u3 = Xb[i3 * 64 + lane];
        a0 += __uint_as_float(u0.x << 16); a1 += __uint_as_float(u0.x & 0xffff0000u);
        a2 += __uint_as_float(u0.y << 16); a3 += __uint_as_float(u0.y & 0xffff0000u);
        a0 += __uint_as_float(u1.x << 16); a1 += __uint_as_float(u1.x & 0xffff0000u);
        a2 += __uint_as_float(u1.y << 16); a3 += __uint_as_float(u1.y & 0xffff0000u);
        a0 += __uint_as_float(u2.x << 16); a1 += __uint_as_float(u2.x & 0xffff0000u);
        a2 += __uint_as_float(u2.y << 16); a3 += __uint_as_float(u2.y & 0xffff0000u);
        a0 += __uint_as_float(u3.x << 16); a1 += __uint_as_float(u3.x & 0xffff0000u);
        a2 += __uint_as_float(u3.y << 16); a3 += __uint_as_float(u3.y & 0xffff0000u);
    }
    for (; j < e; ++j) {
        const uint2 u = Xb[ci[j] * 64 + lane];
        a0 += __uint_as_float(u.x << 16); a1 += __uint_as_float(u.x & 0xffff0000u);
        a2 += __uint_as_float(u.y << 16); a3 += __uint_as_float(u.y & 0xffff0000u);
    }
    uint2 o;
    o.x = (uint32_t)f2b(a0 * inv) | ((uint32_t)f2b(a1 * inv) << 16);
    o.y = (uint32_t)f2b(a2 * inv) | ((uint32_t)f2b(a3 * inv) << 16);
    ((uint2*)(M + ((size_t)bag * NNODES + node) * DENC))[lane] = o;
}

// ---------------------------------------------------------------------------
// classifier (fp32): out[b] = relu(emb[b]@Wc1 + bc1) @ Wc2 + bc2
// ---------------------------------------------------------------------------
__global__ __launch_bounds__(128)
void classifier_kernel(const float* __restrict__ emb, const float* __restrict__ Wc1,
                       const float* __restrict__ bc1, const float* __restrict__ Wc2,
                       const float* __restrict__ bc2, float* __restrict__ out)
{
    const int b = blockIdx.x;
    const int t = threadIdx.x;  // 128
    __shared__ float se[DENC];
    se[t] = emb[b * DENC + t];
    se[128 + t] = emb[b * DENC + 128 + t];
    __syncthreads();
    float h = bc1[t];
    for (int k = 0; k < DENC; ++k) h = fmaf(se[k], Wc1[k * DFC + t], h);
    h = fmaxf(h, 0.f);
    __shared__ float s0[128], s1[128];
    s0[t] = h * Wc2[t * NCLS + 0];
    s1[t] = h * Wc2[t * NCLS + 1];
    __syncthreads();
    for (int off = 64; off > 0; off >>= 1) {
        if (t < off) { s0[t] += s0[t + off]; s1[t] += s1[t + off]; }
        __syncthreads();
    }
    if (t == 0) {
        out[b * NCLS + 0] = s0[0] + bc2[0];
        out[b * NCLS + 1] = s1[0] + bc2[1];
    }
}

// ---------------------------------------------------------------------------
extern "C" void kernel_launch(void* const* d_in, const int* in_sizes, int n_in,
                              void* d_out, int out_size, void* d_ws, size_t ws_size,
                              hipStream_t stream)
{
    const float* x    = (const float*)d_in[0];
    const int*   edges= (const int*)d_in[1];   // int32 on device
    const float* We   = (const float*)d_in[2];
    const float* be   = (const float*)d_in[3];
    const float* Wl1  = (const float*)d_in[4];
    const float* bl1  = (const float*)d_in[5];
    const float* Wr1  = (const float*)d_in[6];
    const float* Wl2  = (const float*)d_in[7];
    const float* bl2  = (const float*)d_in[8];
    const float* Wr2  = (const float*)d_in[9];
    // d_in[10..12] = Wlp, blp, Wrp: dead (softmax over 1 cluster == 1)
    const float* Wc1  = (const float*)d_in[13];
    const float* bc1  = (const float*)d_in[14];
    const float* Wc2  = (const float*)d_in[15];
    const float* bc2  = (const float*)d_in[16];
    float* out = (float*)d_out;

    auto rnd = [](size_t v) { return (v + 255) & ~(size_t)255; };
    auto bytesFor = [&](int G) -> size_t {
        size_t tot = rnd((size_t)NBAGS * NNODES * DIN * 2);            // xb
        tot += 3 * rnd((size_t)G * NNODES * DENC * 2);                  // H, Mb, Gb
        tot += rnd((size_t)256 * DIN * 2) + 4 * rnd((size_t)256 * DENC * 2); // Wt
        tot += rnd((size_t)G * (NNODES + 1) * 4);                       // rowptr
        tot += 2 * rnd((size_t)G * NNODES * 4);                         // cnt, fill
        tot += rnd((size_t)G * NEDGES * 4);                             // colidx
        tot += rnd((size_t)NBAGS * DENC * 4);                           // emb
        return tot + 1024;
    };
    int G = NBAGS;
    while (G > 1 && bytesFor(G) > ws_size) G >>= 1;

    char* p = (char*)d_ws;
    auto alloc = [&](size_t bytes) -> char* {
        char* r = p; p += rnd(bytes); return r;
    };
    ushort* xb    = (ushort*)alloc((size_t)NBAGS * NNODES * DIN * 2);
    ushort* H     = (ushort*)alloc((size_t)G * NNODES * DENC * 2);  // h, then mean2
    ushort* Mb    = (ushort*)alloc((size_t)G * NNODES * DENC * 2);  // mean1
    ushort* Gb    = (ushort*)alloc((size_t)G * NNODES * DENC * 2);  // g1
    ushort* Wet   = (ushort*)alloc((size_t)256 * DIN * 2);
    ushort* Wl1t  = (ushort*)alloc((size_t)256 * DENC * 2);
    ushort* Wr1t  = (ushort*)alloc((size_t)256 * DENC * 2);
    ushort* Wl2t  = (ushort*)alloc((size_t)256 * DENC * 2);
    ushort* Wr2t  = (ushort*)alloc((size_t)256 * DENC * 2);
    int*    rowptr= (int*)   alloc((size_t)G * (NNODES + 1) * 4);
    int*    cnt   = (int*)   alloc((size_t)G * NNODES * 4);
    int*    fillc = (int*)   alloc((size_t)G * NNODES * 4);
    int*    colidx= (int*)   alloc((size_t)G * NEDGES * 4);
    float*  emb   = (float*) alloc((size_t)NBAGS * DENC * 4);

    // one-time per launch: conversions (ws re-poisoned each call)
    hipMemsetAsync(emb, 0, (size_t)NBAGS * DENC * 4, stream);
    {
        const int n4 = NBAGS * NNODES * DIN / 4;
        cvt_bf16_kernel<<<(n4 + 255) / 256, 256, 0, stream>>>(x, xb, n4);
        wt_transpose_kernel<<<(256 * DIN + 255) / 256, 256, 0, stream>>>(We, Wet, DIN);
        wt_transpose_kernel<<<(256 * DENC + 255) / 256, 256, 0, stream>>>(Wl1, Wl1t, DENC);
        wt_transpose_kernel<<<(256 * DENC + 255) / 256, 256, 0, stream>>>(Wr1, Wr1t, DENC);
        wt_transpose_kernel<<<(256 * DENC + 255) / 256, 256, 0, stream>>>(Wl2, Wl2t, DENC);
        wt_transpose_kernel<<<(256 * DENC + 255) / 256, 256, 0, stream>>>(Wr2, Wr2t, DENC);
    }

    for (int bagBase = 0; bagBase < NBAGS; bagBase += G) {
        const int g = (bagBase + G <= NBAGS) ? G : (NBAGS - bagBase);
        const int rows = g * NNODES;
        const ushort* xg = xb + (size_t)bagBase * NNODES * DIN;
        const int*    eg = edges + (size_t)bagBase * 2 * NEDGES;

        hipMemsetAsync(cnt,   0, (size_t)g * NNODES * 4, stream);
        hipMemsetAsync(fillc, 0, (size_t)g * NNODES * 4, stream);

        dim3 gemm_grid((rows + 127) / 128, 2);
        const int agg_blocks = g * (NNODES / 4);
        const int csr_blocks = g * CSR_BPB;

        // encoder: H = relu(x @ We + be)
        gemm_bf16_kernel<false, true, false><<<gemm_grid, 256, 0, stream>>>(
            xg, Wet, nullptr, nullptr, be, H, nullptr, rows, DIN, bagBase, g);

        // CSR build (shared by both SAGE layers)
        count_kernel<<<csr_blocks, 256, 0, stream>>>(eg, cnt, g);
        scan_kernel<<<g, 1024, 0, stream>>>(cnt, rowptr);
        fill_kernel<<<csr_blocks, 256, 0, stream>>>(eg, rowptr, fillc, colidx, g);

        // layer 1: g1 = relu(mean1@Wl1 + h@Wr1 + bl1)
        agg_mean_kernel<<<agg_blocks, 256, 0, stream>>>(H, rowptr, colidx, Mb, g);
        gemm_bf16_kernel<true, true, false><<<gemm_grid, 256, 0, stream>>>(
            Mb, Wl1t, H, Wr1t, bl1, Gb, nullptr, rows, DENC, bagBase, g);

        // layer 2 fused with emb reduction: emb[bag] += relu(mean2@Wl2 + g1@Wr2 + bl2)
        agg_mean_kernel<<<agg_blocks, 256, 0, stream>>>(Gb, rowptr, colidx, H, g);
        gemm_bf16_kernel<true, true, true><<<gemm_grid, 256, 0, stream>>>(
            H, Wl2t, Gb, Wr2t, bl2, nullptr, emb, rows, DENC, bagBase, g);
    }

    classifier_kernel<<<NBAGS, 128, 0, stream>>>(emb, Wc1, bc1, Wc2, bc2, out);
}